// Round 1
// baseline (347.925 us; speedup 1.0000x reference)
//
#include <hip/hip_runtime.h>
#include <cstdint>
#include <cstddef>

// ---------------------------------------------------------------------------
// MHA forward, bf16 MFMA pipeline.
// B=2, S=2048, D=1024, H=16, dk=64.
// Pipeline:
//   1) prep:   cast q,k,v,Wq,Wk,Wv,Wo fp32->bf16; mask int32 -> additive float
//   2) proj3:  qh = (q@Wq^T + bq)*0.125 (bf16, [B,H,S,64])
//              kh = (k@Wk^T + bk)       (bf16, [B,H,S,64])
//              vhT= (v@Wv^T + bv)^T     (bf16, [B,H,64,S])  <- transposed store
//   3) attn:   flash-style online softmax, 64 q-rows/block, 64-key tiles
//              -> ao bf16 [B,S,H*64] (= [4096,1024] row major)
//   4) oproj:  out = ao@Wo^T + bo (fp32 -> d_out)
// ---------------------------------------------------------------------------

using bf16   = __bf16;
using bf16x4 = __attribute__((ext_vector_type(4))) __bf16;
using bf16x8 = __attribute__((ext_vector_type(8))) __bf16;
using f32x4  = __attribute__((ext_vector_type(4))) float;

#define MFMA_BF16(a, b, c) __builtin_amdgcn_mfma_f32_16x16x32_bf16((a), (b), (c), 0, 0, 0)

// async global->LDS, 16B per lane. LDS dest is wave-uniform base + lane*16.
__device__ __forceinline__ void gload_lds16(const void* g, void* l) {
  __builtin_amdgcn_global_load_lds((__attribute__((address_space(1))) void*)g,
                                   (__attribute__((address_space(3))) void*)l,
                                   16, 0, 0);
}

// ---------------------------------------------------------------------------
// 1) prep: casts + mask
// ---------------------------------------------------------------------------
__global__ __launch_bounds__(256) void prep_kernel(
    const float* __restrict__ q, const float* __restrict__ k, const float* __restrict__ v,
    const int* __restrict__ mask,
    const float* __restrict__ Wq, const float* __restrict__ Wk,
    const float* __restrict__ Wv, const float* __restrict__ Wo,
    bf16* __restrict__ qb, bf16* __restrict__ kb, bf16* __restrict__ vb,
    bf16* __restrict__ Wqb, bf16* __restrict__ Wkb, bf16* __restrict__ Wvb,
    bf16* __restrict__ Wob, float* __restrict__ maskf)
{
  const int NQ = 1048576;   // 4096*1024/4 vec4 groups per q/k/v
  const int NW = 262144;    // 1024*1024/4 per weight
  int i = blockIdx.x * 256 + threadIdx.x;
  if (i < 3 * NQ) {
    const float* src; bf16* dst; int j;
    if (i < NQ)        { src = q; dst = qb; j = i; }
    else if (i < 2*NQ) { src = k; dst = kb; j = i - NQ; }
    else               { src = v; dst = vb; j = i - 2*NQ; }
    float4 f = ((const float4*)src)[j];
    ((bf16x4*)dst)[j] = bf16x4{(bf16)f.x, (bf16)f.y, (bf16)f.z, (bf16)f.w};
  } else if (i < 3*NQ + 4*NW) {
    int j = i - 3*NQ;
    const float* src; bf16* dst;
    if (j < NW)        { src = Wq; dst = Wqb; }
    else if (j < 2*NW) { src = Wk; dst = Wkb; j -= NW; }
    else if (j < 3*NW) { src = Wv; dst = Wvb; j -= 2*NW; }
    else               { src = Wo; dst = Wob; j -= 3*NW; }
    float4 f = ((const float4*)src)[j];
    ((bf16x4*)dst)[j] = bf16x4{(bf16)f.x, (bf16)f.y, (bf16)f.z, (bf16)f.w};
  } else if (i < 3*NQ + 4*NW + 1024) {
    int j = i - 3*NQ - 4*NW;
    int4 mi = ((const int4*)mask)[j];
    float4 o;
    o.x = (mi.x == 0) ? -1e9f : 0.0f;
    o.y = (mi.y == 0) ? -1e9f : 0.0f;
    o.z = (mi.z == 0) ? -1e9f : 0.0f;
    o.w = (mi.w == 0) ? -1e9f : 0.0f;
    ((float4*)maskf)[j] = o;
  }
}

// ---------------------------------------------------------------------------
// Shared GEMM core: C[128x128] tile of A[M,K] @ B[N,K]^T, bf16 in, f32 acc.
// 256 threads = 4 waves in 2x2; each wave owns 64x64 = 4x4 MFMA tiles.
// ---------------------------------------------------------------------------
__device__ __forceinline__ void gemm128_core(const bf16* __restrict__ A,
                                             const bf16* __restrict__ Bw,
                                             int K, int m0, int n0,
                                             bf16* As, bf16* Bs, f32x4 acc[4][4])
{
  const int tid  = threadIdx.x;
  const int w    = tid >> 6;
  const int lane = tid & 63;
  const int wr = w >> 1, wc = w & 1;
  const int quad = lane >> 4, l16 = lane & 15;
  const int srow = lane >> 3;          // 0..7 row within a 1KB chunk
  const int scol = (lane & 7) * 8;     // element offset within row (16B lanes)

#pragma unroll
  for (int mt = 0; mt < 4; ++mt)
#pragma unroll
    for (int nt = 0; nt < 4; ++nt)
      acc[mt][nt] = f32x4{0.f, 0.f, 0.f, 0.f};

  for (int k0 = 0; k0 < K; k0 += 64) {
    // stage 128x64 A-tile and B-tile (16KB each) via global_load_lds
#pragma unroll
    for (int c4 = 0; c4 < 4; ++c4) {
      const int c   = w * 4 + c4;        // chunk 0..15, 1KB each (8 rows)
      const int row = c * 8 + srow;
      gload_lds16(A  + (size_t)(m0 + row) * K + k0 + scol, As + c * 512);
      gload_lds16(Bw + (size_t)(n0 + row) * K + k0 + scol, Bs + c * 512);
    }
    __syncthreads();
#pragma unroll
    for (int kk = 0; kk < 2; ++kk) {
      bf16x8 af[4], bfr[4];
#pragma unroll
      for (int mt = 0; mt < 4; ++mt)
        af[mt] = *(const bf16x8*)(As + (wr*64 + mt*16 + l16) * 64 + kk*32 + quad*8);
#pragma unroll
      for (int nt = 0; nt < 4; ++nt)
        bfr[nt] = *(const bf16x8*)(Bs + (wc*64 + nt*16 + l16) * 64 + kk*32 + quad*8);
#pragma unroll
      for (int mt = 0; mt < 4; ++mt)
#pragma unroll
        for (int nt = 0; nt < 4; ++nt)
          acc[mt][nt] = MFMA_BF16(af[mt], bfr[nt], acc[mt][nt]);
    }
    __syncthreads();
  }
}

// ---------------------------------------------------------------------------
// 2) fused QKV projections (blockIdx.z selects job)
// ---------------------------------------------------------------------------
__global__ __launch_bounds__(256) void proj3_kernel(
    const bf16* __restrict__ Xq, const bf16* __restrict__ Xk, const bf16* __restrict__ Xv,
    const bf16* __restrict__ Wqb, const bf16* __restrict__ Wkb, const bf16* __restrict__ Wvb,
    const float* __restrict__ bq, const float* __restrict__ bk, const float* __restrict__ bv,
    bf16* __restrict__ qh, bf16* __restrict__ kh, bf16* __restrict__ vhT)
{
  __shared__ bf16 As[128 * 64];
  __shared__ bf16 Bs[128 * 64];
  const int z = blockIdx.z;
  const bf16*  X    = (z == 0) ? Xq  : (z == 1) ? Xk  : Xv;
  const bf16*  Wb   = (z == 0) ? Wqb : (z == 1) ? Wkb : Wvb;
  const float* bias = (z == 0) ? bq  : (z == 1) ? bk  : bv;
  const int m0 = blockIdx.x * 128, n0 = blockIdx.y * 128;

  f32x4 acc[4][4];
  gemm128_core(X, Wb, 1024, m0, n0, As, Bs, acc);

  const int tid = threadIdx.x, w = tid >> 6, lane = tid & 63;
  const int wr = w >> 1, wc = w & 1, quad = lane >> 4, l16 = lane & 15;
#pragma unroll
  for (int mt = 0; mt < 4; ++mt) {
#pragma unroll
    for (int nt = 0; nt < 4; ++nt) {
      const int n = n0 + wc*64 + nt*16 + l16;
      const int h = n >> 6, d = n & 63;
      const float bn = bias[n];
#pragma unroll
      for (int r = 0; r < 4; ++r) {
        const int m  = m0 + wr*64 + mt*16 + quad*4 + r;
        const int bb = m >> 11, s = m & 2047;
        const float val = acc[mt][nt][r] + bn;
        if (z == 0)
          qh[(((size_t)bb*16 + h)*2048 + s)*64 + d] = (bf16)(val * 0.125f); // 1/sqrt(dk) exact pow2
        else if (z == 1)
          kh[(((size_t)bb*16 + h)*2048 + s)*64 + d] = (bf16)val;
        else
          vhT[(((size_t)bb*16 + h)*64 + d)*2048 + s] = (bf16)val;           // transposed store
      }
    }
  }
}

// ---------------------------------------------------------------------------
// 3) flash attention. grid: x = q-tile (S/64=32), y = b*H+h (32). 256 thr.
// Each wave owns 16 q rows. 64-key tiles.
// ---------------------------------------------------------------------------
__global__ __launch_bounds__(256) void attn_kernel(
    const bf16* __restrict__ qh, const bf16* __restrict__ kh,
    const bf16* __restrict__ vhT, const float* __restrict__ maskf,
    bf16* __restrict__ out)
{
  __shared__ bf16 Ks[64 * 64];      // [key][d]
  __shared__ bf16 Vs[64 * 64];      // [d][key] (from vhT)
  __shared__ bf16 Ps[4][16 * 64];   // per-wave P staging [q16][key64]

  const int tid = threadIdx.x, w = tid >> 6, lane = tid & 63;
  const int quad = lane >> 4, l16 = lane & 15;
  const int srow = lane >> 3, scol = (lane & 7) * 8;
  const int qt = blockIdx.x, bh = blockIdx.y;
  const int b  = bh >> 4, h = bh & 15;
  const int q0 = qt * 64 + w * 16;                 // this wave's first q row

  // Q fragments (A-layout), kept in registers: q row = q0+l16, k = kk*32+quad*8..
  const bf16* qbase = qh + (((size_t)bh * 2048) + q0) * 64;
  bf16x8 aQ[2];
#pragma unroll
  for (int kk = 0; kk < 2; ++kk)
    aQ[kk] = *(const bf16x8*)(qbase + (size_t)l16 * 64 + kk*32 + quad*8);

  f32x4 Oacc[4];
  float mrow[4], lrow[4];
#pragma unroll
  for (int i = 0; i < 4; ++i) { Oacc[i] = f32x4{0.f,0.f,0.f,0.f}; mrow[i] = -3e38f; lrow[i] = 0.f; }

  const float* mf = maskf + (size_t)b * 2048;

  for (int t = 0; t < 32; ++t) {
    const int kt0 = t * 64;
    // stage K [64key x 64d] and V^T [64d x 64key]
#pragma unroll
    for (int c4 = 0; c4 < 2; ++c4) {
      const int c   = w * 2 + c4;      // chunk 0..7
      const int row = c * 8 + srow;
      gload_lds16(kh  + (((size_t)bh*2048) + kt0 + row) * 64 + scol, Ks + c * 512);
      gload_lds16(vhT + (((size_t)bh*64) + row) * 2048 + kt0 + scol, Vs + c * 512);
    }
    __syncthreads();

    // S = Q K^T  (rows q=quad*4+r, cols key=nt*16+l16)
    f32x4 sac[4];
#pragma unroll
    for (int nt = 0; nt < 4; ++nt) sac[nt] = f32x4{0.f,0.f,0.f,0.f};
#pragma unroll
    for (int kk = 0; kk < 2; ++kk) {
#pragma unroll
      for (int nt = 0; nt < 4; ++nt) {
        bf16x8 bK = *(const bf16x8*)(Ks + (nt*16 + l16) * 64 + kk*32 + quad*8);
        sac[nt] = MFMA_BF16(aQ[kk], bK, sac[nt]);
      }
    }
    // additive mask (key-indexed)
#pragma unroll
    for (int nt = 0; nt < 4; ++nt) {
      const float mv = mf[kt0 + nt*16 + l16];
#pragma unroll
      for (int r = 0; r < 4; ++r) sac[nt][r] += mv;
    }
    // online softmax over this 64-key tile
    float mnew[4], alpha[4];
#pragma unroll
    for (int r = 0; r < 4; ++r) {
      float mx = fmaxf(fmaxf(sac[0][r], sac[1][r]), fmaxf(sac[2][r], sac[3][r]));
#pragma unroll
      for (int off = 1; off < 16; off <<= 1) mx = fmaxf(mx, __shfl_xor(mx, off));
      mnew[r]  = fmaxf(mrow[r], mx);
      alpha[r] = __expf(mrow[r] - mnew[r]);
      mrow[r]  = mnew[r];
    }
    float p[4][4];
#pragma unroll
    for (int nt = 0; nt < 4; ++nt)
#pragma unroll
      for (int r = 0; r < 4; ++r) p[nt][r] = __expf(sac[nt][r] - mnew[r]);
#pragma unroll
    for (int r = 0; r < 4; ++r) {
      float s_ = p[0][r] + p[1][r] + p[2][r] + p[3][r];
#pragma unroll
      for (int off = 1; off < 16; off <<= 1) s_ += __shfl_xor(s_, off);
      lrow[r] = lrow[r] * alpha[r] + s_;
    }
    f32x4 av; for (int r = 0; r < 4; ++r) av[r] = alpha[r];
#pragma unroll
    for (int nt = 0; nt < 4; ++nt) Oacc[nt] *= av;

    // P: C-layout -> A-layout via per-wave LDS round trip
    bf16* Pw = Ps[w];
#pragma unroll
    for (int nt = 0; nt < 4; ++nt)
#pragma unroll
      for (int r = 0; r < 4; ++r)
        Pw[(quad*4 + r) * 64 + nt*16 + l16] = (bf16)p[nt][r];
    // same-wave RAW on LDS: compiler inserts lgkmcnt wait; no barrier needed.

    // O += P V
#pragma unroll
    for (int kk = 0; kk < 2; ++kk) {
      bf16x8 aP = *(const bf16x8*)(Pw + l16 * 64 + kk*32 + quad*8);
#pragma unroll
      for (int nt = 0; nt < 4; ++nt) {
        bf16x8 bV = *(const bf16x8*)(Vs + (nt*16 + l16) * 64 + kk*32 + quad*8);
        Oacc[nt] = MFMA_BF16(aP, bV, Oacc[nt]);
      }
    }
    __syncthreads();   // protect Ks/Vs for next tile's staging
  }

  // epilogue: normalize, store bf16 to ao[b, s, h*64+d]
  float inv[4];
#pragma unroll
  for (int r = 0; r < 4; ++r) inv[r] = 1.0f / lrow[r];
#pragma unroll
  for (int nt = 0; nt < 4; ++nt)
#pragma unroll
    for (int r = 0; r < 4; ++r) {
      const size_t off = ((size_t)b*2048 + q0 + quad*4 + r) * 1024 + h*64 + nt*16 + l16;
      out[off] = (bf16)(Oacc[nt][r] * inv[r]);
    }
}

// ---------------------------------------------------------------------------
// 4) output projection: fp32 result to d_out
// ---------------------------------------------------------------------------
__global__ __launch_bounds__(256) void oproj_kernel(
    const bf16* __restrict__ Ain, const bf16* __restrict__ Wob,
    const float* __restrict__ bo, float* __restrict__ out)
{
  __shared__ bf16 As[128 * 64];
  __shared__ bf16 Bs[128 * 64];
  const int m0 = blockIdx.x * 128, n0 = blockIdx.y * 128;
  f32x4 acc[4][4];
  gemm128_core(Ain, Wob, 1024, m0, n0, As, Bs, acc);

  const int tid = threadIdx.x, w = tid >> 6, lane = tid & 63;
  const int wr = w >> 1, wc = w & 1, quad = lane >> 4, l16 = lane & 15;
#pragma unroll
  for (int mt = 0; mt < 4; ++mt) {
#pragma unroll
    for (int nt = 0; nt < 4; ++nt) {
      const int n = n0 + wc*64 + nt*16 + l16;
      const float bn = bo[n];
#pragma unroll
      for (int r = 0; r < 4; ++r) {
        const int m = m0 + wr*64 + mt*16 + quad*4 + r;
        out[(size_t)m * 1024 + n] = acc[mt][nt][r] + bn;
      }
    }
  }
}

// ---------------------------------------------------------------------------
extern "C" void kernel_launch(void* const* d_in, const int* in_sizes, int n_in,
                              void* d_out, int out_size, void* d_ws, size_t ws_size,
                              hipStream_t stream)
{
  const float* q    = (const float*)d_in[0];
  const float* k    = (const float*)d_in[1];
  const float* v    = (const float*)d_in[2];
  const int*   mask = (const int*)d_in[3];
  const float* Wq   = (const float*)d_in[4];
  const float* bq   = (const float*)d_in[5];
  const float* Wk   = (const float*)d_in[6];
  const float* bk   = (const float*)d_in[7];
  const float* Wv   = (const float*)d_in[8];
  const float* bv   = (const float*)d_in[9];
  const float* Wo   = (const float*)d_in[10];
  const float* bo   = (const float*)d_in[11];

  char* ws = (char*)d_ws;
  bf16*  qb    = (bf16*)(ws);                    // 8 MiB [4096,1024]
  bf16*  kb    = (bf16*)(ws + (8ull  << 20));    // 8 MiB
  bf16*  vb    = (bf16*)(ws + (16ull << 20));    // 8 MiB
  bf16*  Wqb   = (bf16*)(ws + (24ull << 20));    // 2 MiB
  bf16*  Wkb   = (bf16*)(ws + (26ull << 20));    // 2 MiB
  bf16*  Wvb   = (bf16*)(ws + (28ull << 20));    // 2 MiB
  bf16*  Wob   = (bf16*)(ws + (30ull << 20));    // 2 MiB
  float* maskf = (float*)(ws + (32ull << 20));   // 16 KiB
  bf16*  qh    = (bf16*)(ws + (33ull << 20));    // 8 MiB [B,H,S,64]
  bf16*  kh    = (bf16*)(ws + (41ull << 20));    // 8 MiB [B,H,S,64]
  bf16*  vhT   = (bf16*)(ws + (49ull << 20));    // 8 MiB [B,H,64,S]
  bf16*  ao    = (bf16*)(ws);                    // reuse qb region (free after proj3)
  float* out   = (float*)d_out;

  prep_kernel<<<16388, 256, 0, stream>>>(q, k, v, mask, Wq, Wk, Wv, Wo,
                                         qb, kb, vb, Wqb, Wkb, Wvb, Wob, maskf);
  proj3_kernel<<<dim3(32, 8, 3), 256, 0, stream>>>(qb, kb, vb, Wqb, Wkb, Wvb,
                                                   bq, bk, bv, qh, kh, vhT);
  attn_kernel<<<dim3(32, 32), 256, 0, stream>>>(qh, kh, vhT, maskf, ao);
  oproj_kernel<<<dim3(32, 8), 256, 0, stream>>>(ao, Wob, bo, out);
}

// Round 2
// 330.113 us; speedup vs baseline: 1.0540x; 1.0540x over previous
//
#include <hip/hip_runtime.h>
#include <cstdint>
#include <cstddef>

// ---------------------------------------------------------------------------
// MHA forward, bf16 MFMA pipeline.
// B=2, S=2048, D=1024, H=16, dk=64.
// Pipeline:
//   1) prep:   cast q,k,v,Wq,Wk,Wv,Wo fp32->bf16; mask -> additive float (log2 domain)
//   2) proj3:  qh = (q@Wq^T + bq)*0.125*log2e (bf16, [B,H,S,64])
//              kh = (k@Wk^T + bk)             (bf16, [B,H,S,64])
//              vhT= (v@Wv^T + bv)^T           (bf16, [B,H,64,S])
//   3) attn:   S^T=K.Q^T orientation, regs-from-global K/V frags, no barriers
//   4) oproj:  out = ao@Wo^T + bo (fp32 -> d_out)
// ---------------------------------------------------------------------------

using bf16   = __bf16;
using bf16x4 = __attribute__((ext_vector_type(4))) __bf16;
using bf16x8 = __attribute__((ext_vector_type(8))) __bf16;
using f32x4  = __attribute__((ext_vector_type(4))) float;

#define MFMA_BF16(a, b, c) __builtin_amdgcn_mfma_f32_16x16x32_bf16((a), (b), (c), 0, 0, 0)

__device__ __forceinline__ void gload_lds16(const void* g, void* l) {
  __builtin_amdgcn_global_load_lds((__attribute__((address_space(1))) void*)g,
                                   (__attribute__((address_space(3))) void*)l,
                                   16, 0, 0);
}

#define LOG2E 1.4426950408889634f

// ---------------------------------------------------------------------------
// 1) prep: casts + mask (mask in log2 domain: -1e9 * log2e)
// ---------------------------------------------------------------------------
__global__ __launch_bounds__(256) void prep_kernel(
    const float* __restrict__ q, const float* __restrict__ k, const float* __restrict__ v,
    const int* __restrict__ mask,
    const float* __restrict__ Wq, const float* __restrict__ Wk,
    const float* __restrict__ Wv, const float* __restrict__ Wo,
    bf16* __restrict__ qb, bf16* __restrict__ kb, bf16* __restrict__ vb,
    bf16* __restrict__ Wqb, bf16* __restrict__ Wkb, bf16* __restrict__ Wvb,
    bf16* __restrict__ Wob, float* __restrict__ maskf)
{
  const int NQ = 1048576;   // 4096*1024/4 vec4 groups per q/k/v
  const int NW = 262144;    // 1024*1024/4 per weight
  int i = blockIdx.x * 256 + threadIdx.x;
  if (i < 3 * NQ) {
    const float* src; bf16* dst; int j;
    if (i < NQ)        { src = q; dst = qb; j = i; }
    else if (i < 2*NQ) { src = k; dst = kb; j = i - NQ; }
    else               { src = v; dst = vb; j = i - 2*NQ; }
    float4 f = ((const float4*)src)[j];
    ((bf16x4*)dst)[j] = bf16x4{(bf16)f.x, (bf16)f.y, (bf16)f.z, (bf16)f.w};
  } else if (i < 3*NQ + 4*NW) {
    int j = i - 3*NQ;
    const float* src; bf16* dst;
    if (j < NW)        { src = Wq; dst = Wqb; }
    else if (j < 2*NW) { src = Wk; dst = Wkb; j -= NW; }
    else if (j < 3*NW) { src = Wv; dst = Wvb; j -= 2*NW; }
    else               { src = Wo; dst = Wob; j -= 3*NW; }
    float4 f = ((const float4*)src)[j];
    ((bf16x4*)dst)[j] = bf16x4{(bf16)f.x, (bf16)f.y, (bf16)f.z, (bf16)f.w};
  } else if (i < 3*NQ + 4*NW + 1024) {
    int j = i - 3*NQ - 4*NW;
    int4 mi = ((const int4*)mask)[j];
    float4 o;
    o.x = (mi.x == 0) ? -1e9f * LOG2E : 0.0f;
    o.y = (mi.y == 0) ? -1e9f * LOG2E : 0.0f;
    o.z = (mi.z == 0) ? -1e9f * LOG2E : 0.0f;
    o.w = (mi.w == 0) ? -1e9f * LOG2E : 0.0f;
    ((float4*)maskf)[j] = o;
  }
}

// ---------------------------------------------------------------------------
// Shared GEMM core: C[128x128] tile of A[M,K] @ B[N,K]^T, bf16 in, f32 acc.
// ---------------------------------------------------------------------------
__device__ __forceinline__ void gemm128_core(const bf16* __restrict__ A,
                                             const bf16* __restrict__ Bw,
                                             int K, int m0, int n0,
                                             bf16* As, bf16* Bs, f32x4 acc[4][4])
{
  const int tid  = threadIdx.x;
  const int w    = tid >> 6;
  const int lane = tid & 63;
  const int wr = w >> 1, wc = w & 1;
  const int quad = lane >> 4, l16 = lane & 15;
  const int srow = lane >> 3;
  const int scol = (lane & 7) * 8;

#pragma unroll
  for (int mt = 0; mt < 4; ++mt)
#pragma unroll
    for (int nt = 0; nt < 4; ++nt)
      acc[mt][nt] = f32x4{0.f, 0.f, 0.f, 0.f};

  for (int k0 = 0; k0 < K; k0 += 64) {
#pragma unroll
    for (int c4 = 0; c4 < 4; ++c4) {
      const int c   = w * 4 + c4;
      const int row = c * 8 + srow;
      gload_lds16(A  + (size_t)(m0 + row) * K + k0 + scol, As + c * 512);
      gload_lds16(Bw + (size_t)(n0 + row) * K + k0 + scol, Bs + c * 512);
    }
    __syncthreads();
#pragma unroll
    for (int kk = 0; kk < 2; ++kk) {
      bf16x8 af[4], bfr[4];
#pragma unroll
      for (int mt = 0; mt < 4; ++mt)
        af[mt] = *(const bf16x8*)(As + (wr*64 + mt*16 + l16) * 64 + kk*32 + quad*8);
#pragma unroll
      for (int nt = 0; nt < 4; ++nt)
        bfr[nt] = *(const bf16x8*)(Bs + (wc*64 + nt*16 + l16) * 64 + kk*32 + quad*8);
#pragma unroll
      for (int mt = 0; mt < 4; ++mt)
#pragma unroll
        for (int nt = 0; nt < 4; ++nt)
          acc[mt][nt] = MFMA_BF16(af[mt], bfr[nt], acc[mt][nt]);
    }
    __syncthreads();
  }
}

// ---------------------------------------------------------------------------
// 2) fused QKV projections
// ---------------------------------------------------------------------------
__global__ __launch_bounds__(256) void proj3_kernel(
    const bf16* __restrict__ Xq, const bf16* __restrict__ Xk, const bf16* __restrict__ Xv,
    const bf16* __restrict__ Wqb, const bf16* __restrict__ Wkb, const bf16* __restrict__ Wvb,
    const float* __restrict__ bq, const float* __restrict__ bk, const float* __restrict__ bv,
    bf16* __restrict__ qh, bf16* __restrict__ kh, bf16* __restrict__ vhT)
{
  __shared__ bf16 As[128 * 64];
  __shared__ bf16 Bs[128 * 64];
  const int z = blockIdx.z;
  const bf16*  X    = (z == 0) ? Xq  : (z == 1) ? Xk  : Xv;
  const bf16*  Wb   = (z == 0) ? Wqb : (z == 1) ? Wkb : Wvb;
  const float* bias = (z == 0) ? bq  : (z == 1) ? bk  : bv;
  const int m0 = blockIdx.x * 128, n0 = blockIdx.y * 128;

  f32x4 acc[4][4];
  gemm128_core(X, Wb, 1024, m0, n0, As, Bs, acc);

  const int tid = threadIdx.x, w = tid >> 6, lane = tid & 63;
  const int wr = w >> 1, wc = w & 1, quad = lane >> 4, l16 = lane & 15;
#pragma unroll
  for (int mt = 0; mt < 4; ++mt) {
#pragma unroll
    for (int nt = 0; nt < 4; ++nt) {
      const int n = n0 + wc*64 + nt*16 + l16;
      const int h = n >> 6, d = n & 63;
      const float bn = bias[n];
#pragma unroll
      for (int r = 0; r < 4; ++r) {
        const int m  = m0 + wr*64 + mt*16 + quad*4 + r;
        const int bb = m >> 11, s = m & 2047;
        const float val = acc[mt][nt][r] + bn;
        if (z == 0)
          qh[(((size_t)bb*16 + h)*2048 + s)*64 + d] = (bf16)(val * (0.125f * LOG2E));
        else if (z == 1)
          kh[(((size_t)bb*16 + h)*2048 + s)*64 + d] = (bf16)val;
        else
          vhT[(((size_t)bb*16 + h)*64 + d)*2048 + s] = (bf16)val;
      }
    }
  }
}

// ---------------------------------------------------------------------------
// 3) flash attention v2: S^T orientation, K/V frags from global, no barriers.
// grid: (S/128=16, B*H=32), 256 thr = 4 waves; wave w -> 32 q rows.
// ---------------------------------------------------------------------------
#define PSTRIDE 72   // 64 + 8 pad elements: 144B rows rotate banks, 16B aligned

__global__ __launch_bounds__(256, 2) void attn_kernel(
    const bf16* __restrict__ qh, const bf16* __restrict__ kh,
    const bf16* __restrict__ vhT, const float* __restrict__ maskf,
    bf16* __restrict__ out)
{
  __shared__ bf16 Ps[4][16 * PSTRIDE];

  const int tid = threadIdx.x, w = tid >> 6, lane = tid & 63;
  const int quad = lane >> 4, l16 = lane & 15;
  const int bh = blockIdx.y, b = bh >> 4, h = bh & 15;
  const int q0 = blockIdx.x * 128 + w * 32;

  const bf16* kbase = kh  + (size_t)bh * 2048 * 64;
  const bf16* vbase = vhT + (size_t)bh * 64 * 2048;
  const bf16* qbase = qh  + ((size_t)bh * 2048 + q0) * 64;
  const float* mbase = maskf + (size_t)b * 2048;
  bf16* Pw = Ps[w];

  // Q fragments (serve as B-operand for S^T = K.Q^T)
  bf16x8 aQ[2][2];
#pragma unroll
  for (int rb = 0; rb < 2; ++rb)
#pragma unroll
    for (int kk = 0; kk < 2; ++kk)
      aQ[rb][kk] = *(const bf16x8*)(qbase + (size_t)(rb*16 + l16)*64 + kk*32 + quad*8);

  f32x4 Oacc[2][4];          // O^T: row d = mb*16+quad*4+r, col q = l16
  float mrow[2] = {-3e38f, -3e38f}, lrow[2] = {0.f, 0.f};
#pragma unroll
  for (int rb = 0; rb < 2; ++rb)
#pragma unroll
    for (int mb = 0; mb < 4; ++mb) Oacc[rb][mb] = f32x4{0.f,0.f,0.f,0.f};

  // K fragments, double-buffered
  bf16x8 aK[2][8];
#pragma unroll
  for (int mb = 0; mb < 4; ++mb)
#pragma unroll
    for (int kk = 0; kk < 2; ++kk)
      aK[0][mb*2+kk] = *(const bf16x8*)(kbase + (size_t)(mb*16 + l16)*64 + kk*32 + quad*8);

#pragma unroll 2
  for (int t = 0; t < 32; ++t) {
    const int cur = t & 1, nxt = cur ^ 1;
    const int kt0 = t * 64;

    // V^T fragments for this tile (A-operand for O^T = V^T.P^T)
    bf16x8 aV[8];
#pragma unroll
    for (int mb = 0; mb < 4; ++mb)
#pragma unroll
      for (int kk = 0; kk < 2; ++kk)
        aV[mb*2+kk] = *(const bf16x8*)(vbase + (size_t)(mb*16 + l16)*2048 + kt0 + kk*32 + quad*8);

    float4 mk[4];
#pragma unroll
    for (int mb = 0; mb < 4; ++mb)
      mk[mb] = *(const float4*)(mbase + kt0 + mb*16 + quad*4);

#pragma unroll
    for (int rb = 0; rb < 2; ++rb) {
      // S^T tile: rows key = mb*16+quad*4+r, col q = l16
      f32x4 sac[4];
#pragma unroll
      for (int mb = 0; mb < 4; ++mb) sac[mb] = f32x4{0.f,0.f,0.f,0.f};
#pragma unroll
      for (int kk = 0; kk < 2; ++kk)
#pragma unroll
        for (int mb = 0; mb < 4; ++mb)
          sac[mb] = MFMA_BF16(aK[cur][mb*2+kk], aQ[rb][kk], sac[mb]);

      if (rb == 0) {
        // prefetch next tile's K while softmax/PV run
        const int kt0n = ((t + 1) & 31) * 64;
#pragma unroll
        for (int mb = 0; mb < 4; ++mb)
#pragma unroll
          for (int kk = 0; kk < 2; ++kk)
            aK[nxt][mb*2+kk] = *(const bf16x8*)(kbase + (size_t)(kt0n + mb*16 + l16)*64 + kk*32 + quad*8);
      }

      // mask (log2 domain) + online softmax; per-lane scalar state (q = l16)
      float mx = -3e38f;
#pragma unroll
      for (int mb = 0; mb < 4; ++mb)
#pragma unroll
        for (int r = 0; r < 4; ++r) {
          sac[mb][r] += (&mk[mb].x)[r];
          mx = fmaxf(mx, sac[mb][r]);
        }
      mx = fmaxf(mx, __shfl_xor(mx, 16));
      mx = fmaxf(mx, __shfl_xor(mx, 32));
      const float mnew  = fmaxf(mrow[rb], mx);
      const float alpha = exp2f(mrow[rb] - mnew);
      mrow[rb] = mnew;

      float p[4][4];
      float s_ = 0.f;
#pragma unroll
      for (int mb = 0; mb < 4; ++mb)
#pragma unroll
        for (int r = 0; r < 4; ++r) {
          p[mb][r] = exp2f(sac[mb][r] - mnew);
          s_ += p[mb][r];
        }
      s_ += __shfl_xor(s_, 16);
      s_ += __shfl_xor(s_, 32);
      lrow[rb] = lrow[rb] * alpha + s_;

#pragma unroll
      for (int mb = 0; mb < 4; ++mb) Oacc[rb][mb] *= alpha;

      // P round-trip: packed b64 writes, padded rows -> balanced banks
#pragma unroll
      for (int mb = 0; mb < 4; ++mb) {
        bf16x4 pk = bf16x4{(bf16)p[mb][0], (bf16)p[mb][1], (bf16)p[mb][2], (bf16)p[mb][3]};
        *(bf16x4*)(Pw + l16*PSTRIDE + mb*16 + quad*4) = pk;
      }
#pragma unroll
      for (int kk = 0; kk < 2; ++kk) {
        bf16x8 aP = *(const bf16x8*)(Pw + l16*PSTRIDE + kk*32 + quad*8);
#pragma unroll
        for (int mb = 0; mb < 4; ++mb)
          Oacc[rb][mb] = MFMA_BF16(aV[mb*2+kk], aP, Oacc[rb][mb]);
      }
    }
  }

  // epilogue: O^T -> ao[b, s=q, h*64+d], normalize by 1/l (per-lane scalar)
#pragma unroll
  for (int rb = 0; rb < 2; ++rb) {
    const float inv = 1.0f / lrow[rb];
#pragma unroll
    for (int mb = 0; mb < 4; ++mb) {
      bf16x4 o = bf16x4{(bf16)(Oacc[rb][mb][0]*inv), (bf16)(Oacc[rb][mb][1]*inv),
                        (bf16)(Oacc[rb][mb][2]*inv), (bf16)(Oacc[rb][mb][3]*inv)};
      *(bf16x4*)(out + ((size_t)b*2048 + q0 + rb*16 + l16)*1024 + h*64 + mb*16 + quad*4) = o;
    }
  }
}

// ---------------------------------------------------------------------------
// 4) output projection: fp32 result to d_out
// ---------------------------------------------------------------------------
__global__ __launch_bounds__(256) void oproj_kernel(
    const bf16* __restrict__ Ain, const bf16* __restrict__ Wob,
    const float* __restrict__ bo, float* __restrict__ out)
{
  __shared__ bf16 As[128 * 64];
  __shared__ bf16 Bs[128 * 64];
  const int m0 = blockIdx.x * 128, n0 = blockIdx.y * 128;
  f32x4 acc[4][4];
  gemm128_core(Ain, Wob, 1024, m0, n0, As, Bs, acc);

  const int tid = threadIdx.x, w = tid >> 6, lane = tid & 63;
  const int wr = w >> 1, wc = w & 1, quad = lane >> 4, l16 = lane & 15;
#pragma unroll
  for (int mt = 0; mt < 4; ++mt) {
#pragma unroll
    for (int nt = 0; nt < 4; ++nt) {
      const int n = n0 + wc*64 + nt*16 + l16;
      const float bn = bo[n];
#pragma unroll
      for (int r = 0; r < 4; ++r) {
        const int m = m0 + wr*64 + mt*16 + quad*4 + r;
        out[(size_t)m * 1024 + n] = acc[mt][nt][r] + bn;
      }
    }
  }
}

// ---------------------------------------------------------------------------
extern "C" void kernel_launch(void* const* d_in, const int* in_sizes, int n_in,
                              void* d_out, int out_size, void* d_ws, size_t ws_size,
                              hipStream_t stream)
{
  const float* q    = (const float*)d_in[0];
  const float* k    = (const float*)d_in[1];
  const float* v    = (const float*)d_in[2];
  const int*   mask = (const int*)d_in[3];
  const float* Wq   = (const float*)d_in[4];
  const float* bq   = (const float*)d_in[5];
  const float* Wk   = (const float*)d_in[6];
  const float* bk   = (const float*)d_in[7];
  const float* Wv   = (const float*)d_in[8];
  const float* bv   = (const float*)d_in[9];
  const float* Wo   = (const float*)d_in[10];
  const float* bo   = (const float*)d_in[11];

  char* ws = (char*)d_ws;
  bf16*  qb    = (bf16*)(ws);
  bf16*  kb    = (bf16*)(ws + (8ull  << 20));
  bf16*  vb    = (bf16*)(ws + (16ull << 20));
  bf16*  Wqb   = (bf16*)(ws + (24ull << 20));
  bf16*  Wkb   = (bf16*)(ws + (26ull << 20));
  bf16*  Wvb   = (bf16*)(ws + (28ull << 20));
  bf16*  Wob   = (bf16*)(ws + (30ull << 20));
  float* maskf = (float*)(ws + (32ull << 20));
  bf16*  qh    = (bf16*)(ws + (33ull << 20));
  bf16*  kh    = (bf16*)(ws + (41ull << 20));
  bf16*  vhT   = (bf16*)(ws + (49ull << 20));
  bf16*  ao    = (bf16*)(ws);                    // reuse qb region
  float* out   = (float*)d_out;

  prep_kernel<<<16388, 256, 0, stream>>>(q, k, v, mask, Wq, Wk, Wv, Wo,
                                         qb, kb, vb, Wqb, Wkb, Wvb, Wob, maskf);
  proj3_kernel<<<dim3(32, 8, 3), 256, 0, stream>>>(qb, kb, vb, Wqb, Wkb, Wvb,
                                                   bq, bk, bv, qh, kh, vhT);
  attn_kernel<<<dim3(16, 32), 256, 0, stream>>>(qh, kh, vhT, maskf, ao);
  oproj_kernel<<<dim3(32, 8), 256, 0, stream>>>(ao, Wob, bo, out);
}